// Round 3
// baseline (759.287 us; speedup 1.0000x reference)
//
#include <hip/hip_runtime.h>

#define DIM 4096
#define SEQ 2048
#define NH 32
#define HD 128

typedef __bf16 bf16x8 __attribute__((ext_vector_type(8)));
typedef float f32x4 __attribute__((ext_vector_type(4)));

// log2(e) / sqrt(HD): folded into Q so softmax runs in exp2 domain
#define QSCALE 0.12751649736765598f

__device__ inline ushort f2bf(float f) {
    union { float f; unsigned u; } v; v.f = f;
    unsigned r = v.u + 0x7fffu + ((v.u >> 16) & 1u);
    return (ushort)(r >> 16);
}

// ---------------- fused fp32 -> bf16 convert for x + all 4 weights ----------------
__global__ void conv_all(const float* __restrict__ x,  const float* __restrict__ wq,
                         const float* __restrict__ wk, const float* __restrict__ wv,
                         const float* __restrict__ wo,
                         ushort* __restrict__ xb,  ushort* __restrict__ wqb,
                         ushort* __restrict__ wkb, ushort* __restrict__ wvb,
                         ushort* __restrict__ wob) {
    int i = blockIdx.x * 256 + threadIdx.x;   // over (SEQ*DIM + 4*DIM*DIM)/4 float4s
    const float* src; ushort* dst; int off;
    const int n4x = (SEQ * DIM) / 4;          // 2^21
    if (i < n4x) { src = x; dst = xb; off = i; }
    else {
        int j = i - n4x;
        int w = j >> 22;                      // DIM*DIM/4 = 2^22
        off = j & ((1 << 22) - 1);
        src = (w == 0) ? wq : (w == 1) ? wk : (w == 2) ? wv : wo;
        dst = (w == 0) ? wqb : (w == 1) ? wkb : (w == 2) ? wvb : wob;
    }
    float4 v = ((const float4*)src)[off];
    ushort4 o;
    o.x = f2bf(v.x); o.y = f2bf(v.y); o.z = f2bf(v.z); o.w = f2bf(v.w);
    ((ushort4*)dst)[off] = o;
}

// ============================================================================
// 256x256 4-phase GEMM body (m201-density schedule, no sched_barrier pinning).
//   BM=BN=256, BK=64, 512 threads = 8 waves (2M x 4N), per-wave C = 128x64
//   (8x4 frags). LDS = 2x(256x64) per operand = 128 KiB double-buffered.
//   All 4 B-frags held in registers across the tile -> 24 ds_read_b128/wave/
//   tile (floor): reads per phase = 12,4,8,0.
//   Phases (each: {reads|stages} barrier {16 MFMA, setprio-wrapped} barrier):
//     P1: read A-h0(8)+B-h0(4);                     MFMA Q(mh=0,nL)
//     P2: read B-h1(4); stage A-h0,B-h0 of t+2 (4); MFMA Q(0,nR)
//     P3: read A-h1(8); stage B-h1 of t+2 (2);      MFMA Q(1,nL)
//     P4: stage A-h1 of t+2 (2);                    MFMA Q(1,nR); vmcnt(8)
//   Stage-into-current-buffer safety: each half staged in the phase AFTER its
//   last reader (A-h0,B-h0 last read P1; B-h1 last read P2; A-h1 last read P3),
//   separated by a full barrier. Tile t+1 was staged during t-1; boundary
//   vmcnt(8) = "t+1's 8 loads retired, t+2's 8 in flight" (in-order retire).
//   Issue-to-wait slack >= 4 phases for every load. Never vmcnt(0) in steady
//   state. Swizzle: row r stores global 16B-chunk g at LDS pos g^(r&7); frag
//   rows == c (mod 8) so readers use pos (gc^(c&7)) -- conflict-free
//   (SQ_LDS_BANK_CONFLICT == 0 measured on this layout).
// ============================================================================

#define AS1(p) (const __attribute__((address_space(1))) void*)(p)
#define AS3(p) (__attribute__((address_space(3))) void*)(p)
#define FENCE() asm volatile("" ::: "memory")
#define BARRIER() do { FENCE(); __builtin_amdgcn_s_barrier(); FENCE(); } while (0)

__device__ __forceinline__ void gemm256_body(
    const ushort* __restrict__ Ab,   // pre-offset to tile row 0 (row-major, stride K)
    const ushort* __restrict__ Bb,   // pre-offset to tile col 0 (row-major, stride K)
    ushort* __restrict__ sA0, ushort* __restrict__ sA1,
    ushort* __restrict__ sB0, ushort* __restrict__ sB1,
    f32x4 acc[8][4], const int K)
{
    const int tid  = threadIdx.x;
    const int wave = tid >> 6, lane = tid & 63;
    const int quad = lane >> 4, c = lane & 15;
    const int wm = wave >> 2, wn = wave & 3;

    // staging: per global_load_lds a wave covers 8 rows x 64 cols (lane>>3 =
    // row-in-group, lane&7 = LDS chunk pos; fetch global chunk (lane&7)^(lane>>3))
    const int aoff  = (lane >> 3) * K + (((lane & 7) ^ (lane >> 3)) * 8);
    const int sa_r0 = wave * 8;                               // A: + h*64 (+128)
    const int sb_r0 = (wave >> 1) * 64 + (wave & 1) * 16;     // B: + h*32 (+8)

    // fragment read chunk positions for the two K-sub-steps
    const int rp0 = (quad ^ (c & 7)) * 8;
    const int rp1 = ((4 + quad) ^ (c & 7)) * 8;
    const int arow = (wm * 128 + c) * 64;   // + mh*64*64 + mt*16*64
    const int brow = (wn * 64 + c) * 64;    // + nh*32*64 + nt*16*64

#define STAGE_A(dst, h, k0) do { \
    const int _r0 = (h) * 64 + sa_r0; \
    __builtin_amdgcn_global_load_lds(AS1(Ab + (size_t)_r0 * K + (k0) + aoff), \
                                     AS3((dst) + _r0 * 64), 16, 0, 0); \
    const int _r1 = _r0 + 128; \
    __builtin_amdgcn_global_load_lds(AS1(Ab + (size_t)_r1 * K + (k0) + aoff), \
                                     AS3((dst) + _r1 * 64), 16, 0, 0); \
  } while (0)
#define STAGE_B(dst, h, k0) do { \
    const int _r0 = (h) * 32 + sb_r0; \
    __builtin_amdgcn_global_load_lds(AS1(Bb + (size_t)_r0 * K + (k0) + aoff), \
                                     AS3((dst) + _r0 * 64), 16, 0, 0); \
    const int _r1 = _r0 + 8; \
    __builtin_amdgcn_global_load_lds(AS1(Bb + (size_t)_r1 * K + (k0) + aoff), \
                                     AS3((dst) + _r1 * 64), 16, 0, 0); \
  } while (0)

    bf16x8 af[4][2], bfr[4][2];

#define READ_A(buf, mh) do { \
    _Pragma("unroll") \
    for (int _m = 0; _m < 4; ++_m) { \
        af[_m][0] = *(const bf16x8*)&(buf)[arow + (mh) * 4096 + _m * 1024 + rp0]; \
        af[_m][1] = *(const bf16x8*)&(buf)[arow + (mh) * 4096 + _m * 1024 + rp1]; \
    } } while (0)
#define READ_B2(buf, nh) do { \
    _Pragma("unroll") \
    for (int _n = 0; _n < 2; ++_n) { \
        bfr[(nh) * 2 + _n][0] = *(const bf16x8*)&(buf)[brow + (nh) * 2048 + _n * 1024 + rp0]; \
        bfr[(nh) * 2 + _n][1] = *(const bf16x8*)&(buf)[brow + (nh) * 2048 + _n * 1024 + rp1]; \
    } } while (0)
#define MMA_Q(mh, nq) do { \
    __builtin_amdgcn_s_setprio(1); \
    _Pragma("unroll") \
    for (int _kk = 0; _kk < 2; ++_kk) \
    _Pragma("unroll") \
    for (int _m = 0; _m < 4; ++_m) \
    _Pragma("unroll") \
    for (int _n = 0; _n < 2; ++_n) \
        acc[(mh) * 4 + _m][(nq) * 2 + _n] = __builtin_amdgcn_mfma_f32_16x16x32_bf16( \
            af[_m][_kk], bfr[(nq) * 2 + _n][_kk], acc[(mh) * 4 + _m][(nq) * 2 + _n], 0, 0, 0); \
    __builtin_amdgcn_s_setprio(0); \
  } while (0)

    const int NT = K >> 6;

    // prologue: tiles 0 and 1 fully staged; wait tile0 (tile1's 8 stay in flight)
    STAGE_A(sA0, 0, 0);  STAGE_A(sA0, 1, 0);
    STAGE_B(sB0, 0, 0);  STAGE_B(sB0, 1, 0);
    STAGE_A(sA1, 0, 64); STAGE_A(sA1, 1, 64);
    STAGE_B(sB1, 0, 64); STAGE_B(sB1, 1, 64);
    asm volatile("s_waitcnt vmcnt(8)" ::: "memory");
    BARRIER();

#pragma unroll 1
    for (int t = 0; t < NT; ++t) {
        ushort* cA = (t & 1) ? sA1 : sA0;
        ushort* cB = (t & 1) ? sB1 : sB0;
        const int kn2 = (t + 2) << 6;
        const bool ok2 = (t + 2 < NT);

        // P1: read A-h0 + B-h0
        READ_A(cA, 0); READ_B2(cB, 0);
        BARRIER();
        MMA_Q(0, 0);
        BARRIER();

        // P2: read B-h1; stage A-h0,B-h0 of t+2 (both last read in P1)
        READ_B2(cB, 1);
        if (ok2) { STAGE_A(cA, 0, kn2); STAGE_B(cB, 0, kn2); }
        BARRIER();
        MMA_Q(0, 1);
        BARRIER();

        // P3: read A-h1; stage B-h1 of t+2 (last read in P2)
        READ_A(cA, 1);
        if (ok2) STAGE_B(cB, 1, kn2);
        BARRIER();
        MMA_Q(1, 0);
        BARRIER();

        // P4: stage A-h1 of t+2 (last read in P3)
        if (ok2) STAGE_A(cA, 1, kn2);
        BARRIER();
        MMA_Q(1, 1);
        if (t < NT - 1) {
            if (ok2) asm volatile("s_waitcnt vmcnt(8)" ::: "memory");
            else     asm volatile("s_waitcnt vmcnt(0)" ::: "memory");
        }
        BARRIER();
    }
#undef STAGE_A
#undef STAGE_B
#undef READ_A
#undef READ_B2
#undef MMA_Q
}

// ---------------- fused QKV GEMM, 256^2 tiles, rotary folded into epilogue ----------------
// Grid 384 (8 m-tiles x 48 n-tiles), XCD n-partition: XCD x=bi&7 owns 6 n-tiles,
// m sweeps fastest (A stays L3-hot; per-XCD B window in its L2).
__global__ __launch_bounds__(512, 2)
void gemm_qkv(const ushort* __restrict__ A,
              const ushort* __restrict__ Bq, const ushort* __restrict__ Bk,
              const ushort* __restrict__ Bv,
              ushort* __restrict__ qout, ushort* __restrict__ kout,
              ushort* __restrict__ vt, const float* __restrict__ freqs) {
    __shared__ __align__(16) ushort sA[2][256 * 64];
    __shared__ __align__(16) ushort sB[2][256 * 64];
    const int bi = blockIdx.x;
    const int x = bi & 7;                    // XCD (round-robin dispatch)
    const int l = bi >> 3;                   // 0..47 within XCD
    const int mblk = l & 7;
    const int nblk = x * 6 + (l >> 3);       // 0..47, exclusive per XCD
    const int wsel = nblk >> 4;              // 0=q 1=k 2=v
    const int nloc = (nblk & 15) * 256;
    const int m0 = mblk * 256;
    const ushort* B = (wsel == 0) ? Bq : (wsel == 1) ? Bk : Bv;

    const f32x4 vzero = {0.f, 0.f, 0.f, 0.f};
    f32x4 acc[8][4];
#pragma unroll
    for (int i = 0; i < 8; i++)
#pragma unroll
        for (int j = 0; j < 4; j++) acc[i][j] = vzero;

    gemm256_body(A + (size_t)m0 * DIM, B + (size_t)nloc * DIM,
                 &sA[0][0], &sA[1][0], &sB[0][0], &sB[1][0], acc, DIM);

    const int tid = threadIdx.x;
    const int wave = tid >> 6, lane = tid & 63;
    const int quad = lane >> 4, c = lane & 15;
    const int wm = wave >> 2, wn = wave & 3;

    if (wsel < 2) {
        ushort* Cw = wsel ? kout : qout;
        const float qs = wsel ? 1.0f : QSCALE;
#pragma unroll
        for (int i = 0; i < 8; i++) {
#pragma unroll
            for (int j = 0; j < 4; j++) {
                int colg = nloc + wn * 64 + j * 16 + c;
                int dh = (colg & 127) >> 1;
#pragma unroll
                for (int r = 0; r < 4; r++) {
                    int row = m0 + wm * 128 + i * 16 + quad * 4 + r;
                    float2 f2 = ((const float2*)freqs)[row * 64 + dh];
                    float f = (f2.x + ((c & 1) ? f2.y : -f2.y)) * qs;
                    Cw[(size_t)row * DIM + colg] = f2bf(acc[i][j][r] * f);
                }
            }
        }
    } else {
        // V: write transposed vt[cv][seq]; lane holds 4 consecutive seq rows
#pragma unroll
        for (int i = 0; i < 8; i++) {
#pragma unroll
            for (int j = 0; j < 4; j++) {
                int cv = nloc + wn * 64 + j * 16 + c;
                int row0 = m0 + wm * 128 + i * 16 + quad * 4;
                ushort4 o;
                o.x = f2bf(acc[i][j][0]); o.y = f2bf(acc[i][j][1]);
                o.z = f2bf(acc[i][j][2]); o.w = f2bf(acc[i][j][3]);
                *(ushort4*)&vt[(size_t)cv * SEQ + row0] = o;
            }
        }
    }
}

// ---------------- bf16 GEMM, 256^2 tiles, fp32 output (final projection) ----------------
// Grid 128 (8 m-tiles x 16 n-tiles), XCD owns 2 n-tiles, m fastest.
__global__ __launch_bounds__(512, 2)
void gemm_f32out(const ushort* __restrict__ A, const ushort* __restrict__ B,
                 float* __restrict__ C, int M, int N, int K) {
    __shared__ __align__(16) ushort sA[2][256 * 64];
    __shared__ __align__(16) ushort sB[2][256 * 64];
    const int bi = blockIdx.x;
    const int x = bi & 7;
    const int l = bi >> 3;                   // 0..15
    const int mblk = l & 7;
    const int nblk = x * 2 + (l >> 3);       // 0..15
    const int m0 = mblk * 256, n0 = nblk * 256;

    const f32x4 vzero = {0.f, 0.f, 0.f, 0.f};
    f32x4 acc[8][4];
#pragma unroll
    for (int i = 0; i < 8; i++)
#pragma unroll
        for (int j = 0; j < 4; j++) acc[i][j] = vzero;

    gemm256_body(A + (size_t)m0 * K, B + (size_t)n0 * K,
                 &sA[0][0], &sA[1][0], &sB[0][0], &sB[1][0], acc, K);

    const int tid = threadIdx.x;
    const int wave = tid >> 6, lane = tid & 63;
    const int quad = lane >> 4, c = lane & 15;
    const int wm = wave >> 2, wn = wave & 3;

#pragma unroll
    for (int i = 0; i < 8; i++)
#pragma unroll
        for (int j = 0; j < 4; j++)
#pragma unroll
            for (int r = 0; r < 4; r++) {
                int row = m0 + wm * 128 + i * 16 + quad * 4 + r;
                int col = n0 + wn * 64 + j * 16 + c;
                C[(size_t)row * N + col] = acc[i][j][r];
            }
}

// ---------------- flash attention (causal), balanced pairing + swizzled LDS ----------------
// 512 blocks: block handles head h = bi&31 and q-block pair {p, 31-p}, p = bi>>5
// -> exactly 33 K-tile iterations per block (perfect balance).
__global__ __launch_bounds__(256)
void flash_kernel(const ushort* __restrict__ Q, const ushort* __restrict__ K,
                  const ushort* __restrict__ Vt, ushort* __restrict__ O) {
    const int bi = blockIdx.x;
    const int h = bi & (NH - 1);
    const int p = bi >> 5;
    __shared__ __align__(16) ushort sK[64 * 128];
    __shared__ __align__(16) ushort sVt[128 * 64];
    __shared__ __align__(16) ushort sP[4][16 * 72];
    const int tid = threadIdx.x, wave = tid >> 6, lane = tid & 63;
    const int quad = lane >> 4, c = lane & 15;

    for (int pass = 0; pass < 2; pass++) {
        const int qb = pass ? (SEQ / 64 - 1 - p) : p;
        const int q0 = qb * 64;

        bf16x8 qf[4];
        {
            const ushort* Qp = Q + (size_t)(q0 + wave * 16 + c) * DIM + h * HD;
#pragma unroll
            for (int ks = 0; ks < 4; ks++) qf[ks] = *(const bf16x8*)(Qp + ks * 32 + quad * 8);
        }
        const f32x4 vzero = {0.f, 0.f, 0.f, 0.f};
        f32x4 oa[8];
#pragma unroll
        for (int dt = 0; dt < 8; dt++) oa[dt] = vzero;
        float ms[4], ls[4];
#pragma unroll
        for (int r = 0; r < 4; r++) { ms[r] = -1e30f; ls[r] = 0.f; }

        for (int kt = 0; kt <= qb; kt++) {
            __syncthreads();
            // stage K tile [64 keys][128 d]: wave covers 16 rows in 4 insts
#pragma unroll
            for (int i = 0; i < 4; i++) {
                int lr = wave * 16 + i * 4 + (lane >> 4);
                int ch = lane & 15;
                int g = (ch & 8) | ((ch ^ lr) & 7);
                __builtin_amdgcn_global_load_lds(
                    (const __attribute__((address_space(1))) void*)(K + (size_t)(kt * 64 + lr) * DIM + h * HD + g * 8),
                    (__attribute__((address_space(3))) void*)(&sK[(wave * 16 + i * 4) * 128]), 16, 0, 0);
            }
            // stage V^T tile [128 d][64 keys]: wave covers 32 rows in 4 insts
#pragma unroll
            for (int i = 0; i < 4; i++) {
                int ld = wave * 32 + i * 8 + (lane >> 3);
                int ch = lane & 7;
                int g = (ch ^ ld) & 7;
                __builtin_amdgcn_global_load_lds(
                    (const __attribute__((address_space(1))) void*)(Vt + (size_t)(h * HD + ld) * SEQ + kt * 64 + g * 8),
                    (__attribute__((address_space(3))) void*)(&sVt[(wave * 32 + i * 8) * 64]), 16, 0, 0);
            }
            __syncthreads();

            // S = Q K^T (Q pre-scaled by log2e/sqrt(HD))
            f32x4 s[4];
#pragma unroll
            for (int nt = 0; nt < 4; nt++) s[nt] = vzero;
#pragma unroll
            for (int ks = 0; ks < 4; ks++)
#pragma unroll
                for (int nt = 0; nt < 4; nt++) {
                    int lr = nt * 16 + c;
                    int gc = ks * 4 + quad;
                    int pch = (gc & 8) | ((gc ^ lr) & 7);
                    bf16x8 kf = *(const bf16x8*)&sK[lr * 128 + pch * 8];
                    s[nt] = __builtin_amdgcn_mfma_f32_16x16x32_bf16(qf[ks], kf, s[nt], 0, 0, 0);
                }

            if (kt == qb) {  // causal mask on the diagonal tile
#pragma unroll
                for (int nt = 0; nt < 4; nt++)
#pragma unroll
                    for (int r = 0; r < 4; r++) {
                        int keyg = nt * 16 + c;
                        int qg   = wave * 16 + quad * 4 + r;
                        if (keyg > qg) s[nt][r] = -1e30f;
                    }
            }

            // online softmax (exp2 domain)
            float mnew[4], alpha[4];
#pragma unroll
            for (int r = 0; r < 4; r++) {
                float v = fmaxf(fmaxf(s[0][r], s[1][r]), fmaxf(s[2][r], s[3][r]));
                v = fmaxf(v, __shfl_xor(v, 1));
                v = fmaxf(v, __shfl_xor(v, 2));
                v = fmaxf(v, __shfl_xor(v, 4));
                v = fmaxf(v, __shfl_xor(v, 8));
                mnew[r]  = fmaxf(ms[r], v);
                alpha[r] = exp2f(ms[r] - mnew[r]);
                ms[r]    = mnew[r];
            }
            float rs[4] = {0.f, 0.f, 0.f, 0.f};
#pragma unroll
            for (int nt = 0; nt < 4; nt++)
#pragma unroll
                for (int r = 0; r < 4; r++) {
                    float pv = exp2f(s[nt][r] - mnew[r]);
                    rs[r] += pv;
                    sP[wave][(quad * 4 + r) * 72 + nt * 16 + c] = f2bf(pv);
                }
#pragma unroll
            for (int r = 0; r < 4; r++) {
                float v = rs[r];
                v += __shfl_xor(v, 1);
                v += __shfl_xor(v, 2);
                v += __shfl_xor(v, 4);
                v += __shfl_xor(v, 8);
                ls[r] = ls[r] * alpha[r] + v;
            }
#pragma unroll
            for (int dt = 0; dt < 8; dt++)
#pragma unroll
                for (int r = 0; r < 4; r++) oa[dt][r] *= alpha[r];

            __asm__ volatile("s_waitcnt lgkmcnt(0)" ::: "memory");  // drain wave-private sP writes

            // O += P V
#pragma unroll
            for (int k2 = 0; k2 < 2; k2++) {
                bf16x8 pf = *(const bf16x8*)&sP[wave][c * 72 + k2 * 32 + quad * 8];
#pragma unroll
                for (int dt = 0; dt < 8; dt++) {
                    int ld = dt * 16 + c;
                    int gc = k2 * 4 + quad;
                    int pch = (gc ^ ld) & 7;
                    bf16x8 vf = *(const bf16x8*)&sVt[ld * 64 + pch * 8];
                    oa[dt] = __builtin_amdgcn_mfma_f32_16x16x32_bf16(pf, vf, oa[dt], 0, 0, 0);
                }
            }
        }

        // epilogue
#pragma unroll
        for (int r = 0; r < 4; r++) {
            float inv = 1.f / ls[r];
            int row = q0 + wave * 16 + quad * 4 + r;
#pragma unroll
            for (int dt = 0; dt < 8; dt++)
                O[(size_t)row * DIM + h * HD + dt * 16 + c] = f2bf(oa[dt][r] * inv);
        }
    }
}

extern "C" void kernel_launch(void* const* d_in, const int* in_sizes, int n_in,
                              void* d_out, int out_size, void* d_ws, size_t ws_size,
                              hipStream_t stream) {
    const float* x     = (const float*)d_in[0];
    const float* freqs = (const float*)d_in[2];
    const float* wq    = (const float*)d_in[4];
    const float* wk    = (const float*)d_in[5];
    const float* wv    = (const float*)d_in[6];
    const float* wo    = (const float*)d_in[7];
    float* out = (float*)d_out;

    ushort* xb    = (ushort*)d_ws;
    ushort* wqb   = xb    + (size_t)SEQ * DIM;
    ushort* wkb   = wqb   + (size_t)DIM * DIM;
    ushort* wvb   = wkb   + (size_t)DIM * DIM;
    ushort* wob   = wvb   + (size_t)DIM * DIM;
    ushort* qbuf  = wob   + (size_t)DIM * DIM;
    ushort* kbuf  = qbuf  + (size_t)SEQ * DIM;
    ushort* vtbuf = kbuf  + (size_t)SEQ * DIM;   // [DIM][SEQ] = V^T per head
    ushort* obuf  = vtbuf + (size_t)SEQ * DIM;

    const int n4tot = (SEQ * DIM + 4 * DIM * DIM) / 4;
    conv_all<<<n4tot / 256, 256, 0, stream>>>(x, wq, wk, wv, wo, xb, wqb, wkb, wvb, wob);

    // 8 m-tiles x (3*16) n-tiles of 256^2
    gemm_qkv<<<dim3(384), 512, 0, stream>>>(xb, wqb, wkb, wvb, qbuf, kbuf, vtbuf, freqs);

    flash_kernel<<<dim3(NH * SEQ / 128), 256, 0, stream>>>(qbuf, kbuf, vtbuf, obuf);

    // 8 m-tiles x 16 n-tiles of 256^2
    gemm_f32out<<<dim3(128), 512, 0, stream>>>(obuf, wob, out, SEQ, DIM, DIM);
}

// Round 4
// 757.194 us; speedup vs baseline: 1.0028x; 1.0028x over previous
//
#include <hip/hip_runtime.h>

#define DIM 4096
#define SEQ 2048
#define NH 32
#define HD 128

typedef __bf16 bf16x8 __attribute__((ext_vector_type(8)));
typedef float f32x4 __attribute__((ext_vector_type(4)));

// log2(e) / sqrt(HD): folded into Q so softmax runs in exp2 domain
#define QSCALE 0.12751649736765598f

__device__ inline ushort f2bf(float f) {
    union { float f; unsigned u; } v; v.f = f;
    unsigned r = v.u + 0x7fffu + ((v.u >> 16) & 1u);
    return (ushort)(r >> 16);
}

// ---------------- fused fp32 -> bf16 convert for x + all 4 weights ----------------
__global__ void conv_all(const float* __restrict__ x,  const float* __restrict__ wq,
                         const float* __restrict__ wk, const float* __restrict__ wv,
                         const float* __restrict__ wo,
                         ushort* __restrict__ xb,  ushort* __restrict__ wqb,
                         ushort* __restrict__ wkb, ushort* __restrict__ wvb,
                         ushort* __restrict__ wob) {
    int i = blockIdx.x * 256 + threadIdx.x;   // over (SEQ*DIM + 4*DIM*DIM)/4 float4s
    const float* src; ushort* dst; int off;
    const int n4x = (SEQ * DIM) / 4;          // 2^21
    if (i < n4x) { src = x; dst = xb; off = i; }
    else {
        int j = i - n4x;
        int w = j >> 22;                      // DIM*DIM/4 = 2^22
        off = j & ((1 << 22) - 1);
        src = (w == 0) ? wq : (w == 1) ? wk : (w == 2) ? wv : wo;
        dst = (w == 0) ? wqb : (w == 1) ? wkb : (w == 2) ? wvb : wob;
    }
    float4 v = ((const float4*)src)[off];
    ushort4 o;
    o.x = f2bf(v.x); o.y = f2bf(v.y); o.z = f2bf(v.z); o.w = f2bf(v.w);
    ((ushort4*)dst)[off] = o;
}

// ============================================================================
// 256x256 4-phase GEMM body (m201-density schedule, no sched_barrier pinning).
//   BM=BN=256, BK=64, 512 threads = 8 waves (2M x 4N), per-wave C = 128x64
//   (8x4 frags). LDS = 2x(256x64) per operand = 128 KiB double-buffered.
//   All 4 B-frags held in registers across the tile -> 24 ds_read_b128/wave/
//   tile (floor): reads per phase = 12,4,8,0.
//   Phases (each: {reads|stages} barrier {16 MFMA, setprio-wrapped} barrier):
//     P1: read A-h0(8)+B-h0(4);                     MFMA Q(mh=0,nL)
//     P2: read B-h1(4); stage A-h0,B-h0 of t+2 (4); MFMA Q(0,nR)
//     P3: read A-h1(8); stage B-h1 of t+2 (2);      MFMA Q(1,nL)
//     P4: stage A-h1 of t+2 (2);                    MFMA Q(1,nR); vmcnt(8)
//   Stage-into-current-buffer safety: each half staged in the phase AFTER its
//   last reader, separated by a full barrier. Boundary vmcnt(8) = "t+1's 8
//   loads retired, t+2's 8 in flight" (in-order retire). Never vmcnt(0) in
//   steady state. Swizzle: row r stores global 16B-chunk g at LDS pos g^(r&7);
//   frag rows == c (mod 8) -> conflict-free (SQ_LDS_BANK_CONFLICT == 0).
// ============================================================================

#define AS1(p) (const __attribute__((address_space(1))) void*)(p)
#define AS3(p) (__attribute__((address_space(3))) void*)(p)
#define FENCE() asm volatile("" ::: "memory")
#define BARRIER() do { FENCE(); __builtin_amdgcn_s_barrier(); FENCE(); } while (0)

__device__ __forceinline__ void gemm256_body(
    const ushort* __restrict__ Ab,   // pre-offset to tile row 0 (row-major, stride K)
    const ushort* __restrict__ Bb,   // pre-offset to tile col 0 (row-major, stride K)
    ushort* __restrict__ sA0, ushort* __restrict__ sA1,
    ushort* __restrict__ sB0, ushort* __restrict__ sB1,
    f32x4 acc[8][4], const int K)
{
    const int tid  = threadIdx.x;
    const int wave = tid >> 6, lane = tid & 63;
    const int quad = lane >> 4, c = lane & 15;
    const int wm = wave >> 2, wn = wave & 3;

    // staging: per global_load_lds a wave covers 8 rows x 64 cols (lane>>3 =
    // row-in-group, lane&7 = LDS chunk pos; fetch global chunk (lane&7)^(lane>>3))
    const int aoff  = (lane >> 3) * K + (((lane & 7) ^ (lane >> 3)) * 8);
    const int sa_r0 = wave * 8;                               // A: + h*64 (+128)
    const int sb_r0 = (wave >> 1) * 64 + (wave & 1) * 16;     // B: + h*32 (+8)

    // fragment read chunk positions for the two K-sub-steps
    const int rp0 = (quad ^ (c & 7)) * 8;
    const int rp1 = ((4 + quad) ^ (c & 7)) * 8;
    const int arow = (wm * 128 + c) * 64;   // + mh*64*64 + mt*16*64
    const int brow = (wn * 64 + c) * 64;    // + nh*32*64 + nt*16*64

#define STAGE_A(dst, h, k0) do { \
    const int _r0 = (h) * 64 + sa_r0; \
    __builtin_amdgcn_global_load_lds(AS1(Ab + (size_t)_r0 * K + (k0) + aoff), \
                                     AS3((dst) + _r0 * 64), 16, 0, 0); \
    const int _r1 = _r0 + 128; \
    __builtin_amdgcn_global_load_lds(AS1(Ab + (size_t)_r1 * K + (k0) + aoff), \
                                     AS3((dst) + _r1 * 64), 16, 0, 0); \
  } while (0)
#define STAGE_B(dst, h, k0) do { \
    const int _r0 = (h) * 32 + sb_r0; \
    __builtin_amdgcn_global_load_lds(AS1(Bb + (size_t)_r0 * K + (k0) + aoff), \
                                     AS3((dst) + _r0 * 64), 16, 0, 0); \
    const int _r1 = _r0 + 8; \
    __builtin_amdgcn_global_load_lds(AS1(Bb + (size_t)_r1 * K + (k0) + aoff), \
                                     AS3((dst) + _r1 * 64), 16, 0, 0); \
  } while (0)

    bf16x8 af[4][2], bfr[4][2];

#define READ_A(buf, mh) do { \
    _Pragma("unroll") \
    for (int _m = 0; _m < 4; ++_m) { \
        af[_m][0] = *(const bf16x8*)&(buf)[arow + (mh) * 4096 + _m * 1024 + rp0]; \
        af[_m][1] = *(const bf16x8*)&(buf)[arow + (mh) * 4096 + _m * 1024 + rp1]; \
    } } while (0)
#define READ_B2(buf, nh) do { \
    _Pragma("unroll") \
    for (int _n = 0; _n < 2; ++_n) { \
        bfr[(nh) * 2 + _n][0] = *(const bf16x8*)&(buf)[brow + (nh) * 2048 + _n * 1024 + rp0]; \
        bfr[(nh) * 2 + _n][1] = *(const bf16x8*)&(buf)[brow + (nh) * 2048 + _n * 1024 + rp1]; \
    } } while (0)
#define MMA_Q(mh, nq) do { \
    __builtin_amdgcn_s_setprio(1); \
    _Pragma("unroll") \
    for (int _kk = 0; _kk < 2; ++_kk) \
    _Pragma("unroll") \
    for (int _m = 0; _m < 4; ++_m) \
    _Pragma("unroll") \
    for (int _n = 0; _n < 2; ++_n) \
        acc[(mh) * 4 + _m][(nq) * 2 + _n] = __builtin_amdgcn_mfma_f32_16x16x32_bf16( \
            af[_m][_kk], bfr[(nq) * 2 + _n][_kk], acc[(mh) * 4 + _m][(nq) * 2 + _n], 0, 0, 0); \
    __builtin_amdgcn_s_setprio(0); \
  } while (0)

    const int NT = K >> 6;

    // prologue: tiles 0 and 1 fully staged; wait tile0 (tile1's 8 stay in flight)
    STAGE_A(sA0, 0, 0);  STAGE_A(sA0, 1, 0);
    STAGE_B(sB0, 0, 0);  STAGE_B(sB0, 1, 0);
    STAGE_A(sA1, 0, 64); STAGE_A(sA1, 1, 64);
    STAGE_B(sB1, 0, 64); STAGE_B(sB1, 1, 64);
    asm volatile("s_waitcnt vmcnt(8)" ::: "memory");
    BARRIER();

#pragma unroll 1
    for (int t = 0; t < NT; ++t) {
        ushort* cA = (t & 1) ? sA1 : sA0;
        ushort* cB = (t & 1) ? sB1 : sB0;
        const int kn2 = (t + 2) << 6;
        const bool ok2 = (t + 2 < NT);

        // P1: read A-h0 + B-h0
        READ_A(cA, 0); READ_B2(cB, 0);
        BARRIER();
        MMA_Q(0, 0);
        BARRIER();

        // P2: read B-h1; stage A-h0,B-h0 of t+2 (both last read in P1)
        READ_B2(cB, 1);
        if (ok2) { STAGE_A(cA, 0, kn2); STAGE_B(cB, 0, kn2); }
        BARRIER();
        MMA_Q(0, 1);
        BARRIER();

        // P3: read A-h1; stage B-h1 of t+2 (last read in P2)
        READ_A(cA, 1);
        if (ok2) STAGE_B(cB, 1, kn2);
        BARRIER();
        MMA_Q(1, 0);
        BARRIER();

        // P4: stage A-h1 of t+2 (last read in P3)
        if (ok2) STAGE_A(cA, 1, kn2);
        BARRIER();
        MMA_Q(1, 1);
        if (t < NT - 1) {
            if (ok2) asm volatile("s_waitcnt vmcnt(8)" ::: "memory");
            else     asm volatile("s_waitcnt vmcnt(0)" ::: "memory");
        }
        BARRIER();
    }
#undef STAGE_A
#undef STAGE_B
#undef READ_A
#undef READ_B2
#undef MMA_Q
}

// ---------------- fused QKV GEMM, 256^2 tiles, rotary folded into epilogue ----------------
// Grid 384 (8 m-tiles x 48 n-tiles), XCD n-partition: XCD x=bi&7 owns 6 n-tiles,
// m sweeps fastest (A stays L3-hot; per-XCD B window in its L2).
__global__ __launch_bounds__(512, 2)
void gemm_qkv(const ushort* __restrict__ A,
              const ushort* __restrict__ Bq, const ushort* __restrict__ Bk,
              const ushort* __restrict__ Bv,
              ushort* __restrict__ qout, ushort* __restrict__ kout,
              ushort* __restrict__ vt, const float* __restrict__ freqs) {
    __shared__ __align__(16) ushort sA[2][256 * 64];
    __shared__ __align__(16) ushort sB[2][256 * 64];
    const int bi = blockIdx.x;
    const int x = bi & 7;                    // XCD (round-robin dispatch)
    const int l = bi >> 3;                   // 0..47 within XCD
    const int mblk = l & 7;
    const int nblk = x * 6 + (l >> 3);       // 0..47, exclusive per XCD
    const int wsel = nblk >> 4;              // 0=q 1=k 2=v
    const int nloc = (nblk & 15) * 256;
    const int m0 = mblk * 256;
    const ushort* B = (wsel == 0) ? Bq : (wsel == 1) ? Bk : Bv;

    const f32x4 vzero = {0.f, 0.f, 0.f, 0.f};
    f32x4 acc[8][4];
#pragma unroll
    for (int i = 0; i < 8; i++)
#pragma unroll
        for (int j = 0; j < 4; j++) acc[i][j] = vzero;

    gemm256_body(A + (size_t)m0 * DIM, B + (size_t)nloc * DIM,
                 &sA[0][0], &sA[1][0], &sB[0][0], &sB[1][0], acc, DIM);

    const int tid = threadIdx.x;
    const int wave = tid >> 6, lane = tid & 63;
    const int quad = lane >> 4, c = lane & 15;
    const int wm = wave >> 2, wn = wave & 3;

    if (wsel < 2) {
        ushort* Cw = wsel ? kout : qout;
        const float qs = wsel ? 1.0f : QSCALE;
#pragma unroll
        for (int i = 0; i < 8; i++) {
#pragma unroll
            for (int j = 0; j < 4; j++) {
                int colg = nloc + wn * 64 + j * 16 + c;
                int dh = (colg & 127) >> 1;
#pragma unroll
                for (int r = 0; r < 4; r++) {
                    int row = m0 + wm * 128 + i * 16 + quad * 4 + r;
                    float2 f2 = ((const float2*)freqs)[row * 64 + dh];
                    float f = (f2.x + ((c & 1) ? f2.y : -f2.y)) * qs;
                    Cw[(size_t)row * DIM + colg] = f2bf(acc[i][j][r] * f);
                }
            }
        }
    } else {
        // V: write transposed vt[cv][seq]; lane holds 4 consecutive seq rows
#pragma unroll
        for (int i = 0; i < 8; i++) {
#pragma unroll
            for (int j = 0; j < 4; j++) {
                int cv = nloc + wn * 64 + j * 16 + c;
                int row0 = m0 + wm * 128 + i * 16 + quad * 4;
                ushort4 o;
                o.x = f2bf(acc[i][j][0]); o.y = f2bf(acc[i][j][1]);
                o.z = f2bf(acc[i][j][2]); o.w = f2bf(acc[i][j][3]);
                *(ushort4*)&vt[(size_t)cv * SEQ + row0] = o;
            }
        }
    }
}

// ---------------- bf16 GEMM, 256^2 tiles, fp32 output (final projection) ----------------
// Grid 128 (8 m-tiles x 16 n-tiles), XCD owns 2 n-tiles, m fastest.
__global__ __launch_bounds__(512, 2)
void gemm_f32out(const ushort* __restrict__ A, const ushort* __restrict__ B,
                 float* __restrict__ C, int M, int N, int K) {
    __shared__ __align__(16) ushort sA[2][256 * 64];
    __shared__ __align__(16) ushort sB[2][256 * 64];
    const int bi = blockIdx.x;
    const int x = bi & 7;
    const int l = bi >> 3;                   // 0..15
    const int mblk = l & 7;
    const int nblk = x * 2 + (l >> 3);       // 0..15
    const int m0 = mblk * 256, n0 = nblk * 256;

    const f32x4 vzero = {0.f, 0.f, 0.f, 0.f};
    f32x4 acc[8][4];
#pragma unroll
    for (int i = 0; i < 8; i++)
#pragma unroll
        for (int j = 0; j < 4; j++) acc[i][j] = vzero;

    gemm256_body(A + (size_t)m0 * K, B + (size_t)n0 * K,
                 &sA[0][0], &sA[1][0], &sB[0][0], &sB[1][0], acc, K);

    const int tid = threadIdx.x;
    const int wave = tid >> 6, lane = tid & 63;
    const int quad = lane >> 4, c = lane & 15;
    const int wm = wave >> 2, wn = wave & 3;

#pragma unroll
    for (int i = 0; i < 8; i++)
#pragma unroll
        for (int j = 0; j < 4; j++)
#pragma unroll
            for (int r = 0; r < 4; r++) {
                int row = m0 + wm * 128 + i * 16 + quad * 4 + r;
                int col = n0 + wn * 64 + j * 16 + c;
                C[(size_t)row * N + col] = acc[i][j][r];
            }
}

// ---------------- flash attention (causal), double-buffered K/V + counted vmcnt ----------------
// 512 blocks: block handles head h = bi&31 and q-block pair {p, 31-p}, p = bi>>5
// -> exactly 33 K-tile iterations per block (perfect balance).
// K/V tiles double-buffered: tile kt+1's 8 global_load_lds issued at top of
// iteration kt, then s_waitcnt vmcnt(8) (waits ONLY tile kt's loads; per-wave
// in-order retirement) + s_barrier (cross-wave visibility). Trailing barrier
// protects buf[b] from the overwrite at kt+1's stage. Never vmcnt(0) in the
// steady-state loop. LDS 74.8 KB/block -> 2 blocks/CU preserved.
__global__ __launch_bounds__(256)
void flash_kernel(const ushort* __restrict__ Q, const ushort* __restrict__ K,
                  const ushort* __restrict__ Vt, ushort* __restrict__ O) {
    const int bi = blockIdx.x;
    const int h = bi & (NH - 1);
    const int p = bi >> 5;
    __shared__ __align__(16) ushort sK[2][64 * 128];
    __shared__ __align__(16) ushort sVt[2][128 * 64];
    __shared__ __align__(16) ushort sP[4][16 * 72];
    const int tid = threadIdx.x, wave = tid >> 6, lane = tid & 63;
    const int quad = lane >> 4, c = lane & 15;

    // stage K tile [64 keys][128 d] (4 insts/wave) + V^T tile [128 d][64 keys]
    // (4 insts/wave) for tile kt into buffer db. 8 vmcnt ops per wave total.
#define STAGE_KV(db, kt) do { \
    _Pragma("unroll") \
    for (int _i = 0; _i < 4; _i++) { \
        int _lr = wave * 16 + _i * 4 + (lane >> 4); \
        int _ch = lane & 15; \
        int _g = (_ch & 8) | ((_ch ^ _lr) & 7); \
        __builtin_amdgcn_global_load_lds( \
            AS1(K + (size_t)((kt) * 64 + _lr) * DIM + h * HD + _g * 8), \
            AS3(&sK[db][(wave * 16 + _i * 4) * 128]), 16, 0, 0); \
    } \
    _Pragma("unroll") \
    for (int _i = 0; _i < 4; _i++) { \
        int _ld = wave * 32 + _i * 8 + (lane >> 3); \
        int _ch = lane & 7; \
        int _g = (_ch ^ _ld) & 7; \
        __builtin_amdgcn_global_load_lds( \
            AS1(Vt + (size_t)(h * HD + _ld) * SEQ + (kt) * 64 + _g * 8), \
            AS3(&sVt[db][(wave * 32 + _i * 8) * 64]), 16, 0, 0); \
    } } while (0)

    for (int pass = 0; pass < 2; pass++) {
        const int qb = pass ? (SEQ / 64 - 1 - p) : p;
        const int q0 = qb * 64;

        bf16x8 qf[4];
        {
            const ushort* Qp = Q + (size_t)(q0 + wave * 16 + c) * DIM + h * HD;
#pragma unroll
            for (int ks = 0; ks < 4; ks++) qf[ks] = *(const bf16x8*)(Qp + ks * 32 + quad * 8);
        }
        const f32x4 vzero = {0.f, 0.f, 0.f, 0.f};
        f32x4 oa[8];
#pragma unroll
        for (int dt = 0; dt < 8; dt++) oa[dt] = vzero;
        float ms[4], ls[4];
#pragma unroll
        for (int r = 0; r < 4; r++) { ms[r] = -1e30f; ls[r] = 0.f; }

        // prologue: tile 0 into buffer 0 (safe: previous readers of buf0 are
        // behind the trailing barrier of the previous pass/iteration)
        STAGE_KV(0, 0);

#pragma unroll 1
        for (int kt = 0; kt <= qb; kt++) {
            const int b = kt & 1;
            // issue next tile's 8 loads into the other buffer (its last
            // readers finished at kt-1, one barrier behind)
            if (kt < qb) {
                STAGE_KV(b ^ 1, kt + 1);
                asm volatile("s_waitcnt vmcnt(8)" ::: "memory");  // tile kt done
            } else {
                asm volatile("s_waitcnt vmcnt(0)" ::: "memory");
            }
            BARRIER();   // cross-wave: all waves' tile-kt loads retired

            // S = Q K^T (Q pre-scaled by log2e/sqrt(HD))
            f32x4 s[4];
#pragma unroll
            for (int nt = 0; nt < 4; nt++) s[nt] = vzero;
            __builtin_amdgcn_s_setprio(1);
#pragma unroll
            for (int ks = 0; ks < 4; ks++)
#pragma unroll
                for (int nt = 0; nt < 4; nt++) {
                    int lr = nt * 16 + c;
                    int gc = ks * 4 + quad;
                    int pch = (gc & 8) | ((gc ^ lr) & 7);
                    bf16x8 kf = *(const bf16x8*)&sK[b][lr * 128 + pch * 8];
                    s[nt] = __builtin_amdgcn_mfma_f32_16x16x32_bf16(qf[ks], kf, s[nt], 0, 0, 0);
                }
            __builtin_amdgcn_s_setprio(0);

            if (kt == qb) {  // causal mask on the diagonal tile
#pragma unroll
                for (int nt = 0; nt < 4; nt++)
#pragma unroll
                    for (int r = 0; r < 4; r++) {
                        int keyg = nt * 16 + c;
                        int qg   = wave * 16 + quad * 4 + r;
                        if (keyg > qg) s[nt][r] = -1e30f;
                    }
            }

            // online softmax (exp2 domain)
            float mnew[4], alpha[4];
#pragma unroll
            for (int r = 0; r < 4; r++) {
                float v = fmaxf(fmaxf(s[0][r], s[1][r]), fmaxf(s[2][r], s[3][r]));
                v = fmaxf(v, __shfl_xor(v, 1));
                v = fmaxf(v, __shfl_xor(v, 2));
                v = fmaxf(v, __shfl_xor(v, 4));
                v = fmaxf(v, __shfl_xor(v, 8));
                mnew[r]  = fmaxf(ms[r], v);
                alpha[r] = exp2f(ms[r] - mnew[r]);
                ms[r]    = mnew[r];
            }
            float rs[4] = {0.f, 0.f, 0.f, 0.f};
#pragma unroll
            for (int nt = 0; nt < 4; nt++)
#pragma unroll
                for (int r = 0; r < 4; r++) {
                    float pv = exp2f(s[nt][r] - mnew[r]);
                    rs[r] += pv;
                    sP[wave][(quad * 4 + r) * 72 + nt * 16 + c] = f2bf(pv);
                }
#pragma unroll
            for (int r = 0; r < 4; r++) {
                float v = rs[r];
                v += __shfl_xor(v, 1);
                v += __shfl_xor(v, 2);
                v += __shfl_xor(v, 4);
                v += __shfl_xor(v, 8);
                ls[r] = ls[r] * alpha[r] + v;
            }
#pragma unroll
            for (int dt = 0; dt < 8; dt++)
#pragma unroll
                for (int r = 0; r < 4; r++) oa[dt][r] *= alpha[r];

            __asm__ volatile("s_waitcnt lgkmcnt(0)" ::: "memory");  // drain wave-private sP writes

            // O += P V
            __builtin_amdgcn_s_setprio(1);
#pragma unroll
            for (int k2 = 0; k2 < 2; k2++) {
                bf16x8 pf = *(const bf16x8*)&sP[wave][c * 72 + k2 * 32 + quad * 8];
#pragma unroll
                for (int dt = 0; dt < 8; dt++) {
                    int ld = dt * 16 + c;
                    int gc = k2 * 4 + quad;
                    int pch = (gc ^ ld) & 7;
                    bf16x8 vf = *(const bf16x8*)&sVt[b][ld * 64 + pch * 8];
                    oa[dt] = __builtin_amdgcn_mfma_f32_16x16x32_bf16(pf, vf, oa[dt], 0, 0, 0);
                }
            }
            __builtin_amdgcn_s_setprio(0);

            BARRIER();   // all waves done reading buf[b] before kt+1 stages into it
        }

        // epilogue
#pragma unroll
        for (int r = 0; r < 4; r++) {
            float inv = 1.f / ls[r];
            int row = q0 + wave * 16 + quad * 4 + r;
#pragma unroll
            for (int dt = 0; dt < 8; dt++)
                O[(size_t)row * DIM + h * HD + dt * 16 + c] = f2bf(oa[dt][r] * inv);
        }
    }
#undef STAGE_KV
}

extern "C" void kernel_launch(void* const* d_in, const int* in_sizes, int n_in,
                              void* d_out, int out_size, void* d_ws, size_t ws_size,
                              hipStream_t stream) {
    const float* x     = (const float*)d_in[0];
    const float* freqs = (const float*)d_in[2];
    const float* wq    = (const float*)d_in[4];
    const float* wk    = (const float*)d_in[5];
    const float* wv    = (const float*)d_in[6];
    const float* wo    = (const float*)d_in[7];
    float* out = (float*)d_out;

    ushort* xb    = (ushort*)d_ws;
    ushort* wqb   = xb    + (size_t)SEQ * DIM;
    ushort* wkb   = wqb   + (size_t)DIM * DIM;
    ushort* wvb   = wkb   + (size_t)DIM * DIM;
    ushort* wob   = wvb   + (size_t)DIM * DIM;
    ushort* qbuf  = wob   + (size_t)DIM * DIM;
    ushort* kbuf  = qbuf  + (size_t)SEQ * DIM;
    ushort* vtbuf = kbuf  + (size_t)SEQ * DIM;   // [DIM][SEQ] = V^T per head
    ushort* obuf  = vtbuf + (size_t)SEQ * DIM;

    const int n4tot = (SEQ * DIM + 4 * DIM * DIM) / 4;
    conv_all<<<n4tot / 256, 256, 0, stream>>>(x, wq, wk, wv, wo, xb, wqb, wkb, wvb, wob);

    // 8 m-tiles x (3*16) n-tiles of 256^2
    gemm_qkv<<<dim3(384), 512, 0, stream>>>(xb, wqb, wkb, wvb, qbuf, kbuf, vtbuf, freqs);

    flash_kernel<<<dim3(NH * SEQ / 128), 256, 0, stream>>>(qbuf, kbuf, vtbuf, obuf);

    // 8 m-tiles x 16 n-tiles of 256^2
    gemm_f32out<<<dim3(128), 512, 0, stream>>>(obuf, wob, out, SEQ, DIM, DIM);
}

// Round 5
// 697.499 us; speedup vs baseline: 1.0886x; 1.0856x over previous
//
#include <hip/hip_runtime.h>

#define DIM 4096
#define SEQ 2048
#define NH 32
#define HD 128

typedef __bf16 bf16x8 __attribute__((ext_vector_type(8)));
typedef float f32x4 __attribute__((ext_vector_type(4)));

// log2(e) / sqrt(HD): folded into Q so softmax runs in exp2 domain
#define QSCALE 0.12751649736765598f

__device__ inline ushort f2bf(float f) {
    union { float f; unsigned u; } v; v.f = f;
    unsigned r = v.u + 0x7fffu + ((v.u >> 16) & 1u);
    return (ushort)(r >> 16);
}

// ---------------- fused fp32 -> bf16 convert for x + all 4 weights ----------------
__global__ void conv_all(const float* __restrict__ x,  const float* __restrict__ wq,
                         const float* __restrict__ wk, const float* __restrict__ wv,
                         const float* __restrict__ wo,
                         ushort* __restrict__ xb,  ushort* __restrict__ wqb,
                         ushort* __restrict__ wkb, ushort* __restrict__ wvb,
                         ushort* __restrict__ wob) {
    int i = blockIdx.x * 256 + threadIdx.x;   // over (SEQ*DIM + 4*DIM*DIM)/4 float4s
    const float* src; ushort* dst; int off;
    const int n4x = (SEQ * DIM) / 4;          // 2^21
    if (i < n4x) { src = x; dst = xb; off = i; }
    else {
        int j = i - n4x;
        int w = j >> 22;                      // DIM*DIM/4 = 2^22
        off = j & ((1 << 22) - 1);
        src = (w == 0) ? wq : (w == 1) ? wk : (w == 2) ? wv : wo;
        dst = (w == 0) ? wqb : (w == 1) ? wkb : (w == 2) ? wvb : wob;
    }
    float4 v = ((const float4*)src)[off];
    ushort4 o;
    o.x = f2bf(v.x); o.y = f2bf(v.y); o.z = f2bf(v.z); o.w = f2bf(v.w);
    ((ushort4*)dst)[off] = o;
}

// ============================================================================
// 256x256 4-phase GEMM body, balanced-read schedule (m201 "4 or 8" pattern).
//   BM=BN=256, BK=64, 512 threads = 8 waves (2M x 4N), per-wave C = 128x64.
//   LDS = 2x(256x64) per operand = 128 KiB double-buffered.
//   Reads per phase = 8/4/8/4 b128 (24/tile floor), stages = 2/2/2/2.
//   Gray quadrant order (0,0),(0,1),(1,1),(1,0); B-half0 of tile t is read in
//   P4 of tile t-1 (carried across the boundary) so P1 only reads af0.
//   Phases (tile t, X=buf[t&1], YB = next B buffer):
//     P1: read af0(X)[8];  stage B-h0(t+2)->X;           barrier; MMA(0,0); barrier
//     P2: read b1 (X)[4];  stage A-h0(t+2)->X;           barrier; MMA(0,1); barrier
//     P3: read af1(X)[8];  stage B-h1(t+2)->X;           barrier; MMA(1,1); barrier
//     P4: vmcnt(6); barrier; stage A-h1(t+2)->X;
//         barrier; MMA(1,0); read b0(YB)[4];             barrier
//   Safety: every staged region is one full barrier behind its last ds_read
//   (B-h0 last read P4(t-1); A-h0 P1; B-h1 P2; A-h1 P3). vmcnt(6) at P4 head =
//   "tile t+1's 8 loads retired, t+2's 6 in flight" (in-order retirement);
//   the extra barrier makes that visible to all waves before b0(Y) is read.
//   b0 WAR in P4 (MMA uses old b0, read refills it) is register-level; the
//   compiler double-buffers/hazard-guards it. Never vmcnt(0) in steady state.
//   Swizzle: row r stores global 16B-chunk g at LDS pos g^(r&7); frag rows ==
//   c (mod 8) -> conflict-free (SQ_LDS_BANK_CONFLICT == 0 measured).
// ============================================================================

#define AS1(p) (const __attribute__((address_space(1))) void*)(p)
#define AS3(p) (__attribute__((address_space(3))) void*)(p)
#define FENCE() asm volatile("" ::: "memory")
#define BARRIER() do { FENCE(); __builtin_amdgcn_s_barrier(); FENCE(); } while (0)

__device__ __forceinline__ void gemm256_body(
    const ushort* __restrict__ Ab,   // pre-offset to tile row 0 (row-major, stride ldk)
    const ushort* __restrict__ Bb,   // pre-offset to tile col 0 (row-major, stride ldk)
    ushort* __restrict__ sA0, ushort* __restrict__ sA1,
    ushort* __restrict__ sB0, ushort* __restrict__ sB1,
    f32x4 acc[8][4], const int ldk, const int klen)
{
    const int tid  = threadIdx.x;
    const int wave = tid >> 6, lane = tid & 63;
    const int quad = lane >> 4, c = lane & 15;
    const int wm = wave >> 2, wn = wave & 3;

    // staging: per global_load_lds a wave covers 8 rows x 64 cols (lane>>3 =
    // row-in-group, lane&7 = LDS chunk pos; fetch global chunk (lane&7)^(lane>>3))
    const int aoff  = (lane >> 3) * ldk + (((lane & 7) ^ (lane >> 3)) * 8);
    const int sa_r0 = wave * 8;                               // A: + h*64 (+128)
    const int sb_r0 = (wave >> 1) * 64 + (wave & 1) * 16;     // B: + h*32 (+8)

    // fragment read chunk positions for the two K-sub-steps
    const int rp0 = (quad ^ (c & 7)) * 8;
    const int rp1 = ((4 + quad) ^ (c & 7)) * 8;
    const int arow = (wm * 128 + c) * 64;   // + mh*64*64 + mt*16*64
    const int brow = (wn * 64 + c) * 64;    // + nh*32*64 + nt*16*64

#define STAGE_A(dst, h, k0) do { \
    const int _r0 = (h) * 64 + sa_r0; \
    __builtin_amdgcn_global_load_lds(AS1(Ab + (size_t)_r0 * ldk + (k0) + aoff), \
                                     AS3((dst) + _r0 * 64), 16, 0, 0); \
    const int _r1 = _r0 + 128; \
    __builtin_amdgcn_global_load_lds(AS1(Ab + (size_t)_r1 * ldk + (k0) + aoff), \
                                     AS3((dst) + _r1 * 64), 16, 0, 0); \
  } while (0)
#define STAGE_B(dst, h, k0) do { \
    const int _r0 = (h) * 32 + sb_r0; \
    __builtin_amdgcn_global_load_lds(AS1(Bb + (size_t)_r0 * ldk + (k0) + aoff), \
                                     AS3((dst) + _r0 * 64), 16, 0, 0); \
    const int _r1 = _r0 + 8; \
    __builtin_amdgcn_global_load_lds(AS1(Bb + (size_t)_r1 * ldk + (k0) + aoff), \
                                     AS3((dst) + _r1 * 64), 16, 0, 0); \
  } while (0)

    bf16x8 af[4][2];        // current A half (4 m-frags x 2 kk)
    bf16x8 b0[2][2];        // B n-half 0 (carried across tile boundary)
    bf16x8 b1[2][2];        // B n-half 1

#define READ_AH(buf, mh) do { \
    _Pragma("unroll") \
    for (int _m = 0; _m < 4; ++_m) { \
        af[_m][0] = *(const bf16x8*)&(buf)[arow + (mh) * 4096 + _m * 1024 + rp0]; \
        af[_m][1] = *(const bf16x8*)&(buf)[arow + (mh) * 4096 + _m * 1024 + rp1]; \
    } } while (0)
#define READ_BH(buf, nh, dst) do { \
    _Pragma("unroll") \
    for (int _n = 0; _n < 2; ++_n) { \
        dst[_n][0] = *(const bf16x8*)&(buf)[brow + (nh) * 2048 + _n * 1024 + rp0]; \
        dst[_n][1] = *(const bf16x8*)&(buf)[brow + (nh) * 2048 + _n * 1024 + rp1]; \
    } } while (0)
#define MMA_Q(mh, nq, B) do { \
    __builtin_amdgcn_s_setprio(1); \
    _Pragma("unroll") \
    for (int _kk = 0; _kk < 2; ++_kk) \
    _Pragma("unroll") \
    for (int _m = 0; _m < 4; ++_m) \
    _Pragma("unroll") \
    for (int _n = 0; _n < 2; ++_n) \
        acc[(mh) * 4 + _m][(nq) * 2 + _n] = __builtin_amdgcn_mfma_f32_16x16x32_bf16( \
            af[_m][_kk], B[_n][_kk], acc[(mh) * 4 + _m][(nq) * 2 + _n], 0, 0, 0); \
    __builtin_amdgcn_s_setprio(0); \
  } while (0)

    const int NT = klen >> 6;

    // prologue: tiles 0 and 1 fully staged; wait tile0 (tile1's 8 in flight);
    // pre-read b0 of tile0 (the carried operand)
    STAGE_B(sB0, 0, 0);  STAGE_A(sA0, 0, 0);
    STAGE_B(sB0, 1, 0);  STAGE_A(sA0, 1, 0);
    STAGE_B(sB1, 0, 64); STAGE_A(sA1, 0, 64);
    STAGE_B(sB1, 1, 64); STAGE_A(sA1, 1, 64);
    asm volatile("s_waitcnt vmcnt(8)" ::: "memory");
    BARRIER();
    READ_BH(sB0, 0, b0);
    BARRIER();

#pragma unroll 1
    for (int t = 0; t < NT; ++t) {
        ushort* cA = (t & 1) ? sA1 : sA0;
        ushort* cB = (t & 1) ? sB1 : sB0;
        ushort* nB = (t & 1) ? sB0 : sB1;
        const int kn2 = (t + 2) << 6;
        const bool ok1 = (t + 1 < NT), ok2 = (t + 2 < NT);

        // P1: read af0; stage B-h0 of t+2 (region last read P4 of t-1)
        READ_AH(cA, 0);
        if (ok2) STAGE_B(cB, 0, kn2);
        BARRIER();
        MMA_Q(0, 0, b0);
        BARRIER();

        // P2: read b1; stage A-h0 of t+2 (last read P1)
        READ_BH(cB, 1, b1);
        if (ok2) STAGE_A(cA, 0, kn2);
        BARRIER();
        MMA_Q(0, 1, b1);
        BARRIER();

        // P3: read af1; stage B-h1 of t+2 (last read P2)
        READ_AH(cA, 1);
        if (ok2) STAGE_B(cB, 1, kn2);
        BARRIER();
        MMA_Q(1, 1, b1);
        BARRIER();

        // P4: vmcnt(6)+barrier (t+1 fully visible); stage A-h1 of t+2 (last
        // read P3); MFMA; then read next tile's b0 from the OTHER B buffer.
        if (ok1) {
            if (ok2) asm volatile("s_waitcnt vmcnt(6)" ::: "memory");
            else     asm volatile("s_waitcnt vmcnt(0)" ::: "memory");
            BARRIER();
            if (ok2) STAGE_A(cA, 1, kn2);
        }
        BARRIER();
        MMA_Q(1, 0, b0);
        if (ok1) READ_BH(nB, 0, b0);
        BARRIER();
    }
#undef STAGE_A
#undef STAGE_B
#undef READ_AH
#undef READ_BH
#undef MMA_Q
}

// ---------------- fused QKV GEMM, 256^2 tiles, rotary folded into epilogue ----------------
// Grid 384 (8 m-tiles x 48 n-tiles), XCD n-partition: XCD x=bi&7 owns 6 n-tiles,
// m sweeps fastest (A stays L3-hot; per-XCD B window in its L2).
__global__ __launch_bounds__(512, 2)
void gemm_qkv(const ushort* __restrict__ A,
              const ushort* __restrict__ Bq, const ushort* __restrict__ Bk,
              const ushort* __restrict__ Bv,
              ushort* __restrict__ qout, ushort* __restrict__ kout,
              ushort* __restrict__ vt, const float* __restrict__ freqs) {
    __shared__ __align__(16) ushort sA[2][256 * 64];
    __shared__ __align__(16) ushort sB[2][256 * 64];
    const int bi = blockIdx.x;
    const int x = bi & 7;                    // XCD (round-robin dispatch)
    const int l = bi >> 3;                   // 0..47 within XCD
    const int mblk = l & 7;
    const int nblk = x * 6 + (l >> 3);       // 0..47, exclusive per XCD
    const int wsel = nblk >> 4;              // 0=q 1=k 2=v
    const int nloc = (nblk & 15) * 256;
    const int m0 = mblk * 256;
    const ushort* B = (wsel == 0) ? Bq : (wsel == 1) ? Bk : Bv;

    const f32x4 vzero = {0.f, 0.f, 0.f, 0.f};
    f32x4 acc[8][4];
#pragma unroll
    for (int i = 0; i < 8; i++)
#pragma unroll
        for (int j = 0; j < 4; j++) acc[i][j] = vzero;

    gemm256_body(A + (size_t)m0 * DIM, B + (size_t)nloc * DIM,
                 &sA[0][0], &sA[1][0], &sB[0][0], &sB[1][0], acc, DIM, DIM);

    const int tid = threadIdx.x;
    const int wave = tid >> 6, lane = tid & 63;
    const int quad = lane >> 4, c = lane & 15;
    const int wm = wave >> 2, wn = wave & 3;

    if (wsel < 2) {
        ushort* Cw = wsel ? kout : qout;
        const float qs = wsel ? 1.0f : QSCALE;
#pragma unroll
        for (int i = 0; i < 8; i++) {
#pragma unroll
            for (int j = 0; j < 4; j++) {
                int colg = nloc + wn * 64 + j * 16 + c;
                int dh = (colg & 127) >> 1;
#pragma unroll
                for (int r = 0; r < 4; r++) {
                    int row = m0 + wm * 128 + i * 16 + quad * 4 + r;
                    float2 f2 = ((const float2*)freqs)[row * 64 + dh];
                    float f = (f2.x + ((c & 1) ? f2.y : -f2.y)) * qs;
                    Cw[(size_t)row * DIM + colg] = f2bf(acc[i][j][r] * f);
                }
            }
        }
    } else {
        // V: write transposed vt[cv][seq]; lane holds 4 consecutive seq rows
#pragma unroll
        for (int i = 0; i < 8; i++) {
#pragma unroll
            for (int j = 0; j < 4; j++) {
                int cv = nloc + wn * 64 + j * 16 + c;
                int row0 = m0 + wm * 128 + i * 16 + quad * 4;
                ushort4 o;
                o.x = f2bf(acc[i][j][0]); o.y = f2bf(acc[i][j][1]);
                o.z = f2bf(acc[i][j][2]); o.w = f2bf(acc[i][j][3]);
                *(ushort4*)&vt[(size_t)cv * SEQ + row0] = o;
            }
        }
    }
}

// ---------------- bf16 GEMM, 256^2 tiles, split-K x2, f32 outputs ----------------
// Grid 256 = 2 K-halves x (8 m x 16 n) -> full-GPU single round (vs 128 blocks
// = half the CUs idle). kh=0 writes C, kh=1 writes partial P; add_partial sums.
__global__ __launch_bounds__(512, 2)
void gemm_f32out(const ushort* __restrict__ A, const ushort* __restrict__ B,
                 float* __restrict__ C, float* __restrict__ P,
                 int M, int N, int K) {
    __shared__ __align__(16) ushort sA[2][256 * 64];
    __shared__ __align__(16) ushort sB[2][256 * 64];
    const int bi = blockIdx.x;
    const int kh = bi >> 7;                  // K-half
    const int r  = bi & 127;
    const int x = r & 7;
    const int l = r >> 3;                    // 0..15
    const int mblk = l & 7;
    const int nblk = x * 2 + (l >> 3);       // 0..15
    const int m0 = mblk * 256, n0 = nblk * 256;
    const int khalf = K >> 1;

    const f32x4 vzero = {0.f, 0.f, 0.f, 0.f};
    f32x4 acc[8][4];
#pragma unroll
    for (int i = 0; i < 8; i++)
#pragma unroll
        for (int j = 0; j < 4; j++) acc[i][j] = vzero;

    gemm256_body(A + (size_t)m0 * K + kh * khalf, B + (size_t)n0 * K + kh * khalf,
                 &sA[0][0], &sA[1][0], &sB[0][0], &sB[1][0], acc, K, khalf);

    const int tid = threadIdx.x;
    const int wave = tid >> 6, lane = tid & 63;
    const int quad = lane >> 4, c = lane & 15;
    const int wm = wave >> 2, wn = wave & 3;
    float* dst = kh ? P : C;

#pragma unroll
    for (int i = 0; i < 8; i++)
#pragma unroll
        for (int j = 0; j < 4; j++)
#pragma unroll
            for (int r2 = 0; r2 < 4; r2++) {
                int row = m0 + wm * 128 + i * 16 + quad * 4 + r2;
                int col = n0 + wn * 64 + j * 16 + c;
                dst[(size_t)row * N + col] = acc[i][j][r2];
            }
}

// C += P (f32, float4-vectorized). 2048*4096 floats / 4 / 256 = 8192 blocks.
__global__ void add_partial(float* __restrict__ C, const float* __restrict__ P) {
    int i = blockIdx.x * 256 + threadIdx.x;
    float4 a = ((const float4*)C)[i];
    float4 b = ((const float4*)P)[i];
    a.x += b.x; a.y += b.y; a.z += b.z; a.w += b.w;
    ((float4*)C)[i] = a;
}

// ---------------- flash attention (causal), double-buffered K/V + counted vmcnt ----------------
// 512 blocks: block handles head h = bi&31 and q-block pair {p, 31-p}, p = bi>>5
// -> exactly 33 K-tile iterations per block (perfect balance).
__global__ __launch_bounds__(256)
void flash_kernel(const ushort* __restrict__ Q, const ushort* __restrict__ K,
                  const ushort* __restrict__ Vt, ushort* __restrict__ O) {
    const int bi = blockIdx.x;
    const int h = bi & (NH - 1);
    const int p = bi >> 5;
    __shared__ __align__(16) ushort sK[2][64 * 128];
    __shared__ __align__(16) ushort sVt[2][128 * 64];
    __shared__ __align__(16) ushort sP[4][16 * 72];
    const int tid = threadIdx.x, wave = tid >> 6, lane = tid & 63;
    const int quad = lane >> 4, c = lane & 15;

#define STAGE_KV(db, kt) do { \
    _Pragma("unroll") \
    for (int _i = 0; _i < 4; _i++) { \
        int _lr = wave * 16 + _i * 4 + (lane >> 4); \
        int _ch = lane & 15; \
        int _g = (_ch & 8) | ((_ch ^ _lr) & 7); \
        __builtin_amdgcn_global_load_lds( \
            AS1(K + (size_t)((kt) * 64 + _lr) * DIM + h * HD + _g * 8), \
            AS3(&sK[db][(wave * 16 + _i * 4) * 128]), 16, 0, 0); \
    } \
    _Pragma("unroll") \
    for (int _i = 0; _i < 4; _i++) { \
        int _ld = wave * 32 + _i * 8 + (lane >> 3); \
        int _ch = lane & 7; \
        int _g = (_ch ^ _ld) & 7; \
        __builtin_amdgcn_global_load_lds( \
            AS1(Vt + (size_t)(h * HD + _ld) * SEQ + (kt) * 64 + _g * 8), \
            AS3(&sVt[db][(wave * 32 + _i * 8) * 64]), 16, 0, 0); \
    } } while (0)

    for (int pass = 0; pass < 2; pass++) {
        const int qb = pass ? (SEQ / 64 - 1 - p) : p;
        const int q0 = qb * 64;

        bf16x8 qf[4];
        {
            const ushort* Qp = Q + (size_t)(q0 + wave * 16 + c) * DIM + h * HD;
#pragma unroll
            for (int ks = 0; ks < 4; ks++) qf[ks] = *(const bf16x8*)(Qp + ks * 32 + quad * 8);
        }
        const f32x4 vzero = {0.f, 0.f, 0.f, 0.f};
        f32x4 oa[8];
#pragma unroll
        for (int dt = 0; dt < 8; dt++) oa[dt] = vzero;
        float ms[4], ls[4];
#pragma unroll
        for (int r = 0; r < 4; r++) { ms[r] = -1e30f; ls[r] = 0.f; }

        STAGE_KV(0, 0);

#pragma unroll 1
        for (int kt = 0; kt <= qb; kt++) {
            const int b = kt & 1;
            if (kt < qb) {
                STAGE_KV(b ^ 1, kt + 1);
                asm volatile("s_waitcnt vmcnt(8)" ::: "memory");  // tile kt done
            } else {
                asm volatile("s_waitcnt vmcnt(0)" ::: "memory");
            }
            BARRIER();   // cross-wave: all waves' tile-kt loads retired

            // S = Q K^T (Q pre-scaled by log2e/sqrt(HD))
            f32x4 s[4];
#pragma unroll
            for (int nt = 0; nt < 4; nt++) s[nt] = vzero;
            __builtin_amdgcn_s_setprio(1);
#pragma unroll
            for (int ks = 0; ks < 4; ks++)
#pragma unroll
                for (int nt = 0; nt < 4; nt++) {
                    int lr = nt * 16 + c;
                    int gc = ks * 4 + quad;
                    int pch = (gc & 8) | ((gc ^ lr) & 7);
                    bf16x8 kf = *(const bf16x8*)&sK[b][lr * 128 + pch * 8];
                    s[nt] = __builtin_amdgcn_mfma_f32_16x16x32_bf16(qf[ks], kf, s[nt], 0, 0, 0);
                }
            __builtin_amdgcn_s_setprio(0);

            if (kt == qb) {  // causal mask on the diagonal tile
#pragma unroll
                for (int nt = 0; nt < 4; nt++)
#pragma unroll
                    for (int r = 0; r < 4; r++) {
                        int keyg = nt * 16 + c;
                        int qg   = wave * 16 + quad * 4 + r;
                        if (keyg > qg) s[nt][r] = -1e30f;
                    }
            }

            // online softmax (exp2 domain)
            float mnew[4], alpha[4];
#pragma unroll
            for (int r = 0; r < 4; r++) {
                float v = fmaxf(fmaxf(s[0][r], s[1][r]), fmaxf(s[2][r], s[3][r]));
                v = fmaxf(v, __shfl_xor(v, 1));
                v = fmaxf(v, __shfl_xor(v, 2));
                v = fmaxf(v, __shfl_xor(v, 4));
                v = fmaxf(v, __shfl_xor(v, 8));
                mnew[r]  = fmaxf(ms[r], v);
                alpha[r] = exp2f(ms[r] - mnew[r]);
                ms[r]    = mnew[r];
            }
            float rs[4] = {0.f, 0.f, 0.f, 0.f};
#pragma unroll
            for (int nt = 0; nt < 4; nt++)
#pragma unroll
                for (int r = 0; r < 4; r++) {
                    float pv = exp2f(s[nt][r] - mnew[r]);
                    rs[r] += pv;
                    sP[wave][(quad * 4 + r) * 72 + nt * 16 + c] = f2bf(pv);
                }
#pragma unroll
            for (int r = 0; r < 4; r++) {
                float v = rs[r];
                v += __shfl_xor(v, 1);
                v += __shfl_xor(v, 2);
                v += __shfl_xor(v, 4);
                v += __shfl_xor(v, 8);
                ls[r] = ls[r] * alpha[r] + v;
            }
#pragma unroll
            for (int dt = 0; dt < 8; dt++)
#pragma unroll
                for (int r = 0; r < 4; r++) oa[dt][r] *= alpha[r];

            __asm__ volatile("s_waitcnt lgkmcnt(0)" ::: "memory");  // drain wave-private sP writes

            // O += P V
            __builtin_amdgcn_s_setprio(1);
#pragma unroll
            for (int k2 = 0; k2 < 2; k2++) {
                bf16x8 pf = *(const bf16x8*)&sP[wave][c * 72 + k2 * 32 + quad * 8];
#pragma unroll
                for (int dt = 0; dt < 8; dt++) {
                    int ld = dt * 16 + c;
                    int gc = k2 * 4 + quad;
                    int pch = (gc ^ ld) & 7;
                    bf16x8 vf = *(const bf16x8*)&sVt[b][ld * 64 + pch * 8];
                    oa[dt] = __builtin_amdgcn_mfma_f32_16x16x32_bf16(pf, vf, oa[dt], 0, 0, 0);
                }
            }
            __builtin_amdgcn_s_setprio(0);

            BARRIER();   // all waves done reading buf[b] before kt+1 stages into it
        }

        // epilogue
#pragma unroll
        for (int r = 0; r < 4; r++) {
            float inv = 1.f / ls[r];
            int row = q0 + wave * 16 + quad * 4 + r;
#pragma unroll
            for (int dt = 0; dt < 8; dt++)
                O[(size_t)row * DIM + h * HD + dt * 16 + c] = f2bf(oa[dt][r] * inv);
        }
    }
#undef STAGE_KV
}

extern "C" void kernel_launch(void* const* d_in, const int* in_sizes, int n_in,
                              void* d_out, int out_size, void* d_ws, size_t ws_size,
                              hipStream_t stream) {
    const float* x     = (const float*)d_in[0];
    const float* freqs = (const float*)d_in[2];
    const float* wq    = (const float*)d_in[4];
    const float* wk    = (const float*)d_in[5];
    const float* wv    = (const float*)d_in[6];
    const float* wo    = (const float*)d_in[7];
    float* out = (float*)d_out;

    ushort* xb    = (ushort*)d_ws;
    ushort* wqb   = xb    + (size_t)SEQ * DIM;
    ushort* wkb   = wqb   + (size_t)DIM * DIM;
    ushort* wvb   = wkb   + (size_t)DIM * DIM;
    ushort* wob   = wvb   + (size_t)DIM * DIM;
    ushort* qbuf  = wob   + (size_t)DIM * DIM;
    ushort* kbuf  = qbuf  + (size_t)SEQ * DIM;
    ushort* vtbuf = kbuf  + (size_t)SEQ * DIM;   // [DIM][SEQ] = V^T per head
    ushort* obuf  = vtbuf + (size_t)SEQ * DIM;
    // split-K partial for the final projection: reuse wqb (dead after gemm_qkv)
    // SEQ*DIM f32 = 33.5 MB fits in wqb's DIM*DIM ushorts (33.5 MB) exactly.
    float* pbuf = (float*)wqb;

    const int n4tot = (SEQ * DIM + 4 * DIM * DIM) / 4;
    conv_all<<<n4tot / 256, 256, 0, stream>>>(x, wq, wk, wv, wo, xb, wqb, wkb, wvb, wob);

    // 8 m-tiles x (3*16) n-tiles of 256^2
    gemm_qkv<<<dim3(384), 512, 0, stream>>>(xb, wqb, wkb, wvb, qbuf, kbuf, vtbuf, freqs);

    flash_kernel<<<dim3(NH * SEQ / 128), 256, 0, stream>>>(qbuf, kbuf, vtbuf, obuf);

    // split-K x2: 256 blocks (full GPU), kh=0 -> out, kh=1 -> pbuf; then sum
    gemm_f32out<<<dim3(256), 512, 0, stream>>>(obuf, wob, out, pbuf, SEQ, DIM, DIM);
    add_partial<<<dim3(SEQ * DIM / 4 / 256), 256, 0, stream>>>(out, pbuf);
}